// Round 3
// baseline (124.793 us; speedup 1.0000x reference)
//
#include <hip/hip_runtime.h>

// CenterLoss, closed form (clamp provably inactive: pairwise sq-dists are
// 4096 +- ~130, far inside [1e-12,1e12]; absmax=0 verified many rounds):
//   Sum_all  = C*Sx + B*Sc - 2*S2,  S2 = sc . colsum(x), sc = colsum(centers)
//   Sum_diag = Sx + Scl - 2*Sdot
//   loss = Sum_diag/B - 0.001*(Sum_all - Sum_diag)/(B*(C-1))
//
// Round-2 post-mortem: full-prefetch MLP was NEUTRAL (111.9 us) -> not
// source-level-latency-bound (compiler had already hoisted loads). Fixed
// harness cost ~64 us (fill 41 + restores 23, both >80% HBM peak).
// Controllable ~48 us vs ~15-20 us floor. Remaining hypotheses:
//   H1 gather L2 misses (<=128 MiB HBM), H2 launch gaps, H3 sched tail.
// Round-3 design: attack all three:
//  - S2 = sc.colsum(x): x-path independent of centers -> fuse centers+x
//    into ONE kernel (centers blocks overlap x blocks + warm LLC).
//  - 1024 fat x-blocks (8 rows x full width): single scheduling round,
//    each center row gathered once per block (was twice).
//  - nontemporal x loads: read-once stream won't evict centers from L2.
//  - 3 kernels instead of 4 (main, folds, finalize).

typedef float f32x4 __attribute__((ext_vector_type(4)));

#define DD 2048
#define NB 8192
#define NC 1000
#define D4 (DD / 4)            // 512 float4 per row
#define THREADS 256
#define XROWS 8
#define XBLK (NB / XROWS)      // 1024 x-blocks
#define CTILES 8
#define CRG 8
#define CBLOCKS (CTILES * CRG) // 64 centers blocks
#define GRID1 (CBLOCKS + XBLK) // 1088

// ws layout (bytes), all write-before-read (ws is poisoned每iter):
//   cq    [CRG][2048] f32   @ 0       (64 KB)  centers colsum partials
//   sc    [2048]      f32   @ 65536   (8 KB)   final centers colsum
//   csq   [CBLOCKS]   f32   @ 73728   (256 B)  per-block Sc partials
//   part  [XBLK]    float4  @ 73984   (16 KB)  per-x-block {sx,sdot,scl,-}
//   csx   [512]     float4  @ 90368   (8 KB)   colsum(x)
//   xpart [XBLK][512] f4    @ 131072  (8 MB)   per-x-block column sums
#define CQ_OFF    0
#define SC_OFF    65536
#define CSQ_OFF   73728
#define PART_OFF  73984
#define CSX_OFF   90368
#define XPART_OFF 131072

__device__ __forceinline__ float dot4(float4 a, float4 b) {
    return a.x * b.x + a.y * b.y + a.z * b.z + a.w * b.w;
}
__device__ __forceinline__ void acc4(float4& a, float4 b) {
    a.x += b.x; a.y += b.y; a.z += b.z; a.w += b.w;
}
__device__ __forceinline__ float4 ntload(const float4* p) {
    f32x4 v = __builtin_nontemporal_load((const f32x4*)p);
    return make_float4(v[0], v[1], v[2], v[3]);
}

// Kernel 1: fused. Blocks 0..63: centers colsum partials + csq.
// Blocks 64..1087: x rows -> {sx, sdot, scl} + per-column xsum partials.
__global__ __launch_bounds__(THREADS, 4) void main_kernel(
        const float4* __restrict__ x4, const float4* __restrict__ c4,
        const int* __restrict__ labels, float4* __restrict__ cq,
        float* __restrict__ csq_part, float4* __restrict__ part,
        float4* __restrict__ xpart) {
    const int t = threadIdx.x;

    if (blockIdx.x < CBLOCKS) {
        // ---- centers path (dispatched first: warms LLC for gathers) ----
        const int bid = blockIdx.x;
        const int tile = bid & (CTILES - 1);
        const int rg = bid >> 3;
        const int col4 = tile * 64 + (t & 63);
        const int rlane = t >> 6;             // 0..3
        const int row0 = rg * 125;

        float4 acc = make_float4(0.f, 0.f, 0.f, 0.f);
        float csq = 0.f;
#pragma unroll 4
        for (int r = rlane; r < 125; r += 4) {
            float4 v = c4[(size_t)(row0 + r) * D4 + col4];
            acc4(acc, v);
            csq += dot4(v, v);
        }

        __shared__ float4 lds[4][64];
        lds[rlane][t & 63] = acc;
        __syncthreads();
        if (t < 64) {
            float4 s = lds[0][t];
            acc4(s, lds[1][t]); acc4(s, lds[2][t]); acc4(s, lds[3][t]);
            cq[rg * 512 + tile * 64 + t] = s;
        }

        __shared__ float redc[THREADS / 64];
        for (int off = 32; off > 0; off >>= 1)
            csq += __shfl_down(csq, off, 64);
        if ((t & 63) == 0) redc[t >> 6] = csq;
        __syncthreads();
        if (t == 0)
            csq_part[bid] = redc[0] + redc[1] + redc[2] + redc[3];
        return;
    }

    // ---- x path: block handles 8 rows x full width ----
    const int b = blockIdx.x - CBLOCKS;       // 0..1023
    const int rows0 = b * XROWS;

    const float4* xr = x4 + (size_t)rows0 * D4 + t;
    const float4* cb = c4 + t;

    const int4* l4 = (const int4*)(labels + rows0);
    const int4 la = l4[0], lb = l4[1];
    const int labs[XROWS] = {la.x, la.y, la.z, la.w, lb.x, lb.y, lb.z, lb.w};

    float sx = 0.f, sdot = 0.f, scl = 0.f;
    float4 xs0 = make_float4(0.f, 0.f, 0.f, 0.f);
    float4 xs1 = make_float4(0.f, 0.f, 0.f, 0.f);

    // depth-2 pipeline over rows; x loads nontemporal (read-once stream)
    float4 xa0 = ntload(xr);
    float4 xa1 = ntload(xr + 256);
    float4 ca0 = cb[(size_t)labs[0] * D4];
    float4 ca1 = cb[(size_t)labs[0] * D4 + 256];

#pragma unroll
    for (int r = 0; r < XROWS; ++r) {
        float4 nx0, nx1, nc0, nc1;
        if (r + 1 < XROWS) {
            const size_t xo = (size_t)(r + 1) * D4;
            const size_t co = (size_t)labs[r + 1] * D4;
            nx0 = ntload(xr + xo);
            nx1 = ntload(xr + xo + 256);
            nc0 = cb[co];
            nc1 = cb[co + 256];
        }
        sx   += dot4(xa0, xa0) + dot4(xa1, xa1);
        sdot += dot4(xa0, ca0) + dot4(xa1, ca1);
        scl  += dot4(ca0, ca0) + dot4(ca1, ca1);
        acc4(xs0, xa0);
        acc4(xs1, xa1);
        if (r + 1 < XROWS) { xa0 = nx0; xa1 = nx1; ca0 = nc0; ca1 = nc1; }
    }

    // per-column xsum partials (coalesced 16B/lane stores)
    xpart[(size_t)b * D4 + t] = xs0;
    xpart[(size_t)b * D4 + 256 + t] = xs1;

    // block-reduce the 3 scalars
    __shared__ float red[3][THREADS / 64];
    for (int off = 32; off > 0; off >>= 1) {
        sx   += __shfl_down(sx, off, 64);
        sdot += __shfl_down(sdot, off, 64);
        scl  += __shfl_down(scl, off, 64);
    }
    const int lane = t & 63, wv = t >> 6;
    if (lane == 0) { red[0][wv] = sx; red[1][wv] = sdot; red[2][wv] = scl; }
    __syncthreads();
    if (t == 0) {
        float4 s;
        s.x = red[0][0] + red[0][1] + red[0][2] + red[0][3];
        s.y = red[1][0] + red[1][1] + red[1][2] + red[1][3];
        s.z = red[2][0] + red[2][1] + red[2][2] + red[2][3];
        s.w = 0.f;
        part[b] = s;
    }
}

// Kernel 2: folds. Blocks 0..511: colsum_x[j] = sum_b xpart[b][j].
// Blocks 512..513: sc = fold(cq).
__global__ __launch_bounds__(THREADS) void fold_kernel(
        const float4* __restrict__ xpart, const float4* __restrict__ cq,
        float4* __restrict__ csx, float4* __restrict__ sc4) {
    const int t = threadIdx.x;
    const int j = blockIdx.x;

    if (j < 512) {
        float4 a = make_float4(0.f, 0.f, 0.f, 0.f);
#pragma unroll
        for (int m = 0; m < 4; ++m)
            acc4(a, xpart[(size_t)(t + 256 * m) * D4 + j]);

        __shared__ float4 red[THREADS / 64];
        for (int off = 32; off > 0; off >>= 1) {
            a.x += __shfl_down(a.x, off, 64);
            a.y += __shfl_down(a.y, off, 64);
            a.z += __shfl_down(a.z, off, 64);
            a.w += __shfl_down(a.w, off, 64);
        }
        if ((t & 63) == 0) red[t >> 6] = a;
        __syncthreads();
        if (t == 0) {
            float4 s = red[0];
            acc4(s, red[1]); acc4(s, red[2]); acc4(s, red[3]);
            csx[j] = s;
        }
    } else {
        const int idx = (j - 512) * THREADS + t;   // 0..511
        float4 s = cq[idx];
#pragma unroll
        for (int r = 1; r < CRG; ++r) acc4(s, cq[r * 512 + idx]);
        sc4[idx] = s;
    }
}

// Kernel 3: finalize. part folds + csq + S2 = sc . colsum(x), all double.
__global__ __launch_bounds__(THREADS) void finalize_kernel(
        const float4* __restrict__ part, const float* __restrict__ csq_part,
        const float4* __restrict__ csx, const float4* __restrict__ sc4,
        float* __restrict__ out) {
    const int t = threadIdx.x;

    double sx = 0.0, sdot = 0.0, scl = 0.0, s2 = 0.0, csq = 0.0;
    for (int i = t; i < XBLK; i += THREADS) {
        float4 p = part[i];
        sx += (double)p.x; sdot += (double)p.y; scl += (double)p.z;
    }
    if (t < CBLOCKS) csq = (double)csq_part[t];
    for (int c = t; c < 512; c += THREADS) {
        float4 a = csx[c], s = sc4[c];
        s2 += (double)a.x * s.x + (double)a.y * s.y
            + (double)a.z * s.z + (double)a.w * s.w;
    }

    __shared__ double red[5][THREADS / 64];
    for (int off = 32; off > 0; off >>= 1) {
        sx   += __shfl_down(sx, off, 64);
        sdot += __shfl_down(sdot, off, 64);
        scl  += __shfl_down(scl, off, 64);
        s2   += __shfl_down(s2, off, 64);
        csq  += __shfl_down(csq, off, 64);
    }
    const int lane = t & 63, wv = t >> 6;
    if (lane == 0) {
        red[0][wv] = sx; red[1][wv] = sdot; red[2][wv] = scl;
        red[3][wv] = s2; red[4][wv] = csq;
    }
    __syncthreads();
    if (t == 0) {
        double Sx   = red[0][0] + red[0][1] + red[0][2] + red[0][3];
        double Sdot = red[1][0] + red[1][1] + red[1][2] + red[1][3];
        double Scl  = red[2][0] + red[2][1] + red[2][2] + red[2][3];
        double S2   = red[3][0] + red[3][1] + red[3][2] + red[3][3];
        double Sc   = red[4][0] + red[4][1] + red[4][2] + red[4][3];
        double sum_all  = (double)NC * Sx + (double)NB * Sc - 2.0 * S2;
        double sum_diag = Sx + Scl - 2.0 * Sdot;
        double center_loss = sum_diag / (double)NB;
        double sep_loss =
            (sum_all - sum_diag) / ((double)NB * (double)(NC - 1));
        out[0] = (float)(center_loss - 0.001 * sep_loss);
    }
}

extern "C" void kernel_launch(void* const* d_in, const int* in_sizes, int n_in,
                              void* d_out, int out_size, void* d_ws, size_t ws_size,
                              hipStream_t stream) {
    const float4* x4 = (const float4*)d_in[0];   // [8192, 2048] f32
    const float4* c4 = (const float4*)d_in[1];   // [1000, 2048] f32
    const int* labels = (const int*)d_in[2];     // [8192] i32

    float4* cq = (float4*)((char*)d_ws + CQ_OFF);
    float4* sc = (float4*)((char*)d_ws + SC_OFF);
    float* csq_part = (float*)((char*)d_ws + CSQ_OFF);
    float4* part = (float4*)((char*)d_ws + PART_OFF);
    float4* csx = (float4*)((char*)d_ws + CSX_OFF);
    float4* xpart = (float4*)((char*)d_ws + XPART_OFF);
    float* out = (float*)d_out;

    main_kernel<<<GRID1, THREADS, 0, stream>>>(x4, c4, labels, cq,
                                               csq_part, part, xpart);
    fold_kernel<<<514, THREADS, 0, stream>>>((const float4*)xpart,
                                             (const float4*)cq, csx, sc);
    finalize_kernel<<<1, THREADS, 0, stream>>>((const float4*)part, csq_part,
                                               (const float4*)csx,
                                               (const float4*)sc, out);
}

// Round 4
// 113.197 us; speedup vs baseline: 1.1024x; 1.1024x over previous
//
#include <hip/hip_runtime.h>

// CenterLoss, closed form (clamp provably inactive: pairwise sq-dists are
// 4096 +- ~130, far inside [1e-12,1e12]; absmax=0 verified many rounds):
//   Sum_all  = C*Sx + B*Sc - 2*S2,  S2 = sum_b (x_b . sc), sc = colsum(centers)
//   Sum_diag = Sx + Scl - 2*Sdot
//   loss = Sum_diag/B - 0.001*(Sum_all - Sum_diag)/(B*(C-1))
//
// Session ledger:
//   R1 baseline (XROWS=8 half-width, depth-2): 111.0 us
//   R2 full-prefetch MLP: 111.9 NEUTRAL -> per-wave MLP not binding
//   R3 fused + xpart intermediate + nt-loads: 124.8 REGRESSION -> big
//      intermediates forbidden (re-learned); nt loads unhelpful; reverted.
// Fixed harness cost ~65 us (268MB poison fill 42 us @80% peak + restores).
// Controllable ~46 us, x_kernel ~36 us at ~3.7 TB/s effective.
// Prior-session counter: x_kernel 45% occupancy => VGPR in (64,128] =>
// 4 waves/SIMD. R4 single-variable experiment: XROWS 8->4 (4096 blocks),
// depth-2 pipeline keeps ~5 live float4/thread, __launch_bounds__(256,8)
// pins VGPR<=64 => 8 waves/SIMD => 2x wave residency, same total traffic.
// If occupancy binds: x_kernel -> ~20-24 us (dur ~95-100). If neutral:
// occupancy ruled out; remaining suspect is gather/L2 structural BW.

#define DD 2048
#define NB 8192
#define NC 1000
#define D4 (DD / 4)            // 512 float4 per row
#define HALF4 256              // float4 per half-row
#define THREADS 256
#define XROWS 4
#define XBLOCKS ((NB / XROWS) * 2)   // 4096: row-group x column-half
#define CTILES 8
#define CRG 8
#define CBLOCKS (CTILES * CRG)       // 64

// ws layout (bytes):
//   cq  [CRG][2048] f32  @ 0      (64 KB)  centers colsum partial rows
//   sc  [2048]      f32  @ 65536  (8 KB)   final centers colsum
//   csq [CBLOCKS]   f32  @ 73728  (256 B)  per-block Sc partials
//   part[XBLOCKS] float4 @ 73984  (64 KB)  per-x-block {sx, sdot, scl, s2}
#define CQ_OFF   0
#define SC_OFF   65536
#define CSQ_OFF  73728
#define PART_OFF 73984

__device__ __forceinline__ float dot4(float4 a, float4 b) {
    return a.x * b.x + a.y * b.y + a.z * b.z + a.w * b.w;
}
__device__ __forceinline__ void acc4(float4& a, float4 b) {
    a.x += b.x; a.y += b.y; a.z += b.z; a.w += b.w;
}

// Kernel 1: centers -> cq (8 partial colsum rows) + csq partials.
// 64 blocks = 8 col-tiles x 8 row-groups of 125 rows.
__global__ __launch_bounds__(THREADS) void centers_kernel(
        const float4* __restrict__ c4, float4* __restrict__ cq,
        float* __restrict__ csq_part) {
    const int t = threadIdx.x;
    const int tile = blockIdx.x & (CTILES - 1);
    const int rg = blockIdx.x >> 3;
    const int col4 = tile * 64 + (t & 63);
    const int rlane = t >> 6;                 // 0..3
    const int row0 = rg * 125;

    float4 acc = make_float4(0.f, 0.f, 0.f, 0.f);
    float csq = 0.f;
#pragma unroll 4
    for (int r = rlane; r < 125; r += 4) {
        float4 v = c4[(size_t)(row0 + r) * D4 + col4];
        acc4(acc, v);
        csq += dot4(v, v);
    }

    __shared__ float4 lds[4][64];
    lds[rlane][t & 63] = acc;
    __syncthreads();
    if (t < 64) {
        float4 s = lds[0][t];
        acc4(s, lds[1][t]); acc4(s, lds[2][t]); acc4(s, lds[3][t]);
        cq[rg * 512 + tile * 64 + t] = s;
    }

    __shared__ float red[THREADS / 64];
    for (int off = 32; off > 0; off >>= 1) csq += __shfl_down(csq, off, 64);
    const int lane = t & 63, wv = t >> 6;
    if (lane == 0) red[wv] = csq;
    __syncthreads();
    if (t == 0)
        csq_part[blockIdx.x] = red[0] + red[1] + red[2] + red[3];
}

// Kernel 2: fold cq[8][2048] -> sc[2048]. 2 blocks x 256 threads,
// one float4 column each, 8 independent L2-hot loads.
__global__ __launch_bounds__(THREADS) void sc_fold_kernel(
        const float4* __restrict__ cq, float4* __restrict__ sc4) {
    const int idx = blockIdx.x * THREADS + threadIdx.x;   // 0..511
    float4 s = cq[idx];
#pragma unroll
    for (int r = 1; r < CRG; ++r) acc4(s, cq[r * 512 + idx]);
    sc4[idx] = s;
}

// Kernel 3: x -> {sx, sdot, scl, s2} per block. 4096 blocks: row-group
// (4 rows) x column-half (1024 cols). Depth-2 pipeline, ~5 live float4
// per thread, VGPR pinned <=64 by __launch_bounds__ => 8 waves/SIMD.
__global__ __launch_bounds__(THREADS, 8) void x_kernel(
        const float4* __restrict__ x4, const float4* __restrict__ c4,
        const int* __restrict__ labels, const float4* __restrict__ sc4,
        float4* __restrict__ partials) {
    const int t = threadIdx.x;
    const int b = blockIdx.x;
    const int rowgrp = b >> 1;
    const int h = (b & 1) * HALF4;          // float4 offset of this half
    const int rows0 = rowgrp * XROWS;

    const float4* xr = x4 + (size_t)rows0 * D4 + h + t;
    const float4* cbase = c4 + h + t;

    // Labels: 4 x i32, rows0 % 4 == 0 -> one 16B int4 load.
    const int4 la = *(const int4*)(labels + rows0);
    const int labs[XROWS] = {la.x, la.y, la.z, la.w};

    const float4 sc = sc4[h + t];

    float4 xa = xr[0],      ca = cbase[(size_t)labs[0] * D4];
    float4 xb = xr[D4],     cb = cbase[(size_t)labs[1] * D4];

    float sx = 0.f, sdot = 0.f, scl = 0.f, s2 = 0.f;

#pragma unroll
    for (int r = 0; r < XROWS; ++r) {
        float4 nx, nc;
        if (r + 2 < XROWS) {
            nx = xr[(size_t)(r + 2) * D4];
            nc = cbase[(size_t)labs[r + 2] * D4];
        }
        sx   += dot4(xa, xa);
        sdot += dot4(xa, ca);
        scl  += dot4(ca, ca);
        s2   += dot4(xa, sc);
        xa = xb; ca = cb;
        if (r + 2 < XROWS) { xb = nx; cb = nc; }
    }

    __shared__ float red[4][THREADS / 64];
    for (int off = 32; off > 0; off >>= 1) {
        sx   += __shfl_down(sx, off, 64);
        sdot += __shfl_down(sdot, off, 64);
        scl  += __shfl_down(scl, off, 64);
        s2   += __shfl_down(s2, off, 64);
    }
    const int lane = t & 63, wv = t >> 6;
    if (lane == 0) {
        red[0][wv] = sx; red[1][wv] = sdot;
        red[2][wv] = scl; red[3][wv] = s2;
    }
    __syncthreads();
    if (t == 0) {
        float4 s;
        s.x = red[0][0] + red[0][1] + red[0][2] + red[0][3];
        s.y = red[1][0] + red[1][1] + red[1][2] + red[1][3];
        s.z = red[2][0] + red[2][1] + red[2][2] + red[2][3];
        s.w = red[3][0] + red[3][1] + red[3][2] + red[3][3];
        partials[b] = s;
    }
}

__global__ __launch_bounds__(THREADS) void finalize_kernel(
        const float4* __restrict__ partials, const float* __restrict__ csq_part,
        float* __restrict__ out) {
    const int t = threadIdx.x;

    double sx = 0.0, sdot = 0.0, scl = 0.0, s2 = 0.0, csq = 0.0;
    for (int i = t; i < XBLOCKS; i += THREADS) {
        float4 p = partials[i];
        sx += (double)p.x; sdot += (double)p.y;
        scl += (double)p.z; s2 += (double)p.w;
    }
    if (t < CBLOCKS) csq = (double)csq_part[t];

    __shared__ double red[5][THREADS / 64];
    for (int off = 32; off > 0; off >>= 1) {
        sx   += __shfl_down(sx, off, 64);
        sdot += __shfl_down(sdot, off, 64);
        scl  += __shfl_down(scl, off, 64);
        s2   += __shfl_down(s2, off, 64);
        csq  += __shfl_down(csq, off, 64);
    }
    const int lane = t & 63, wv = t >> 6;
    if (lane == 0) {
        red[0][wv] = sx; red[1][wv] = sdot; red[2][wv] = scl;
        red[3][wv] = s2; red[4][wv] = csq;
    }
    __syncthreads();
    if (t == 0) {
        double Sx   = red[0][0] + red[0][1] + red[0][2] + red[0][3];
        double Sdot = red[1][0] + red[1][1] + red[1][2] + red[1][3];
        double Scl  = red[2][0] + red[2][1] + red[2][2] + red[2][3];
        double S2   = red[3][0] + red[3][1] + red[3][2] + red[3][3];
        double Sc   = red[4][0] + red[4][1] + red[4][2] + red[4][3];
        double sum_all  = (double)NC * Sx + (double)NB * Sc - 2.0 * S2;
        double sum_diag = Sx + Scl - 2.0 * Sdot;
        double center_loss = sum_diag / (double)NB;
        double sep_loss =
            (sum_all - sum_diag) / ((double)NB * (double)(NC - 1));
        out[0] = (float)(center_loss - 0.001 * sep_loss);
    }
}

extern "C" void kernel_launch(void* const* d_in, const int* in_sizes, int n_in,
                              void* d_out, int out_size, void* d_ws, size_t ws_size,
                              hipStream_t stream) {
    const float4* x4 = (const float4*)d_in[0];   // [8192, 2048] f32
    const float4* c4 = (const float4*)d_in[1];   // [1000, 2048] f32
    const int* labels = (const int*)d_in[2];     // [8192] i32

    float4* cq = (float4*)((char*)d_ws + CQ_OFF);
    float4* sc = (float4*)((char*)d_ws + SC_OFF);
    float* csq_part = (float*)((char*)d_ws + CSQ_OFF);
    float4* partials = (float4*)((char*)d_ws + PART_OFF);
    float* out = (float*)d_out;

    centers_kernel<<<CBLOCKS, THREADS, 0, stream>>>(c4, cq, csq_part);
    sc_fold_kernel<<<2, THREADS, 0, stream>>>((const float4*)cq, sc);
    x_kernel<<<XBLOCKS, THREADS, 0, stream>>>(x4, c4, labels,
                                              (const float4*)sc, partials);
    finalize_kernel<<<1, THREADS, 0, stream>>>(partials, csq_part, out);
}